// Round 1
// baseline (528.791 us; speedup 1.0000x reference)
//
#include <hip/hip_runtime.h>
#include <cstddef>

#define THREADS 256
#define DDIM 2048

// One block per row. 256 threads x 8 elements = 2048 = D.
// Row is held entirely in registers; x read once, out written once.
// Exact k-th-largest via 4-round MSB-first radix select (8-bit digits)
// over the |x_norm| bit patterns (non-negative floats order as uints).
__global__ __launch_bounds__(THREADS) void sparse_topk_rmsnorm_kernel(
    const float* __restrict__ x,
    const float* __restrict__ weight,
    const float* __restrict__ gamma,
    const int* __restrict__ kp,
    float* __restrict__ out)
{
    const int tid  = threadIdx.x;
    const int lane = tid & 63;
    const int wid  = tid >> 6;
    const long row = blockIdx.x;

    __shared__ unsigned hist[256];
    __shared__ float    wsumf[4];
    __shared__ unsigned wtot[4];
    __shared__ unsigned s_prefix;
    __shared__ unsigned s_kk;

    const float4* x4 = (const float4*)(x + row * (long)DDIM);
    const float4* w4 = (const float4*)weight;
    const float4* g4 = (const float4*)gamma;

    // coalesced: consecutive lanes hit consecutive 16B
    float4 a  = x4[tid];
    float4 b  = x4[tid + 256];
    float4 wa = w4[tid];
    float4 wb = w4[tid + 256];

    // ---- sum of squares -> rms ----
    float ss = a.x*a.x + a.y*a.y + a.z*a.z + a.w*a.w
             + b.x*b.x + b.y*b.y + b.z*b.z + b.w*b.w;
    #pragma unroll
    for (int off = 32; off > 0; off >>= 1)
        ss += __shfl_down(ss, off, 64);
    if (lane == 0) wsumf[wid] = ss;
    __syncthreads();
    const float total = wsumf[0] + wsumf[1] + wsumf[2] + wsumf[3];
    const float rms = rsqrtf(total * (1.0f / (float)DDIM) + 1e-6f);

    // ---- x_norm and magnitude bits ----
    float nx[8];
    unsigned mb[8];
    nx[0] = a.x * rms * wa.x;  nx[1] = a.y * rms * wa.y;
    nx[2] = a.z * rms * wa.z;  nx[3] = a.w * rms * wa.w;
    nx[4] = b.x * rms * wb.x;  nx[5] = b.y * rms * wb.y;
    nx[6] = b.z * rms * wb.z;  nx[7] = b.w * rms * wb.w;
    #pragma unroll
    for (int i = 0; i < 8; ++i)
        mb[i] = __float_as_uint(fabsf(nx[i]));

    // ---- radix select: exact k-th largest magnitude ----
    unsigned kk = (unsigned)kp[0];   // k = 256 in this problem
    unsigned prefix = 0;

    #pragma unroll
    for (int shift = 24; shift >= 0; shift -= 8) {
        const unsigned mask_hi = (shift == 24) ? 0u : (0xFFFFFFFFu << (shift + 8));
        hist[tid] = 0;
        __syncthreads();
        #pragma unroll
        for (int i = 0; i < 8; ++i) {
            if ((mb[i] & mask_hi) == prefix)
                atomicAdd(&hist[(mb[i] >> shift) & 255u], 1u);
        }
        __syncthreads();
        // suffix-sum over 256 bins: cge[tid] = sum_{j>=tid} hist[j]
        const unsigned c0 = hist[tid];
        unsigned c = c0;
        #pragma unroll
        for (int off = 1; off < 64; off <<= 1) {
            unsigned t = __shfl_down(c, off, 64);
            if (lane + off < 64) c += t;
        }
        if (lane == 0) wtot[wid] = c;   // wave's bin total (suffix from its first bin)
        __syncthreads();
        unsigned cge = c;
        #pragma unroll
        for (int w = 0; w < 4; ++w)
            if (w > wid) cge += wtot[w];
        const unsigned cgt = cge - c0;  // count strictly greater than this bin
        if (cgt < kk && kk <= cge) {    // unique crossing bin
            s_prefix = prefix | ((unsigned)tid << shift);
            s_kk = kk - cgt;
        }
        __syncthreads();
        prefix = s_prefix;
        kk = s_kk;
    }

    const unsigned thr = prefix;  // exact bit pattern of k-th largest |x_norm|

    // ---- epilogue: out = x + (|xn| >= thr) * xn * gamma ----
    float4 ga = g4[tid];
    float4 gb = g4[tid + 256];
    float4 o1, o2;
    o1.x = a.x + (mb[0] >= thr ? nx[0] * ga.x : 0.0f);
    o1.y = a.y + (mb[1] >= thr ? nx[1] * ga.y : 0.0f);
    o1.z = a.z + (mb[2] >= thr ? nx[2] * ga.z : 0.0f);
    o1.w = a.w + (mb[3] >= thr ? nx[3] * ga.w : 0.0f);
    o2.x = b.x + (mb[4] >= thr ? nx[4] * gb.x : 0.0f);
    o2.y = b.y + (mb[5] >= thr ? nx[5] * gb.y : 0.0f);
    o2.z = b.z + (mb[6] >= thr ? nx[6] * gb.z : 0.0f);
    o2.w = b.w + (mb[7] >= thr ? nx[7] * gb.w : 0.0f);

    float4* out4 = (float4*)(out + row * (long)DDIM);
    out4[tid]       = o1;
    out4[tid + 256] = o2;
}

extern "C" void kernel_launch(void* const* d_in, const int* in_sizes, int n_in,
                              void* d_out, int out_size, void* d_ws, size_t ws_size,
                              hipStream_t stream) {
    const float* x      = (const float*)d_in[0];
    const float* weight = (const float*)d_in[1];
    const float* gamma  = (const float*)d_in[2];
    const int*   kp     = (const int*)d_in[3];
    const int D = in_sizes[1];          // 2048
    const int N = in_sizes[0] / D;      // 32768
    (void)n_in; (void)out_size; (void)d_ws; (void)ws_size;

    sparse_topk_rmsnorm_kernel<<<dim3(N), dim3(THREADS), 0, stream>>>(
        x, weight, gamma, kp, (float*)d_out);
}

// Round 2
// 459.115 us; speedup vs baseline: 1.1518x; 1.1518x over previous
//
#include <hip/hip_runtime.h>
#include <cstddef>

#define THREADS 256
#define DDIM 2048
#define NBINS 2048

// One block per row; 256 threads x 8 f32 in registers. x read once, out
// written once. Exact k-th largest |x_norm| via 3-round MSB-first radix
// select (11/11/9-bit digits over bits [30:0]; bit 31 = sign = 0 after abs).
// Round 1 digit starts at bit 30 so all 2048 bins are live -> ~5x less
// same-address LDS atomic serialization than an 8-bit top digit on
// RMS-normalized data.
__global__ __launch_bounds__(THREADS) void sparse_topk_rmsnorm_kernel(
    const float* __restrict__ x,
    const float* __restrict__ weight,
    const float* __restrict__ gamma,
    const int* __restrict__ kp,
    float* __restrict__ out)
{
    const int tid  = threadIdx.x;
    const int lane = tid & 63;
    const int wid  = tid >> 6;
    const long row = blockIdx.x;

    __shared__ unsigned hist[NBINS];
    __shared__ float    wsumf[4];
    __shared__ unsigned wtot[4];
    __shared__ unsigned s_prefix;
    __shared__ unsigned s_kk;

    const float4* x4 = (const float4*)(x + row * (long)DDIM);
    const float4* w4 = (const float4*)weight;
    const float4* g4 = (const float4*)gamma;

    // coalesced: consecutive lanes hit consecutive 16B
    float4 a  = x4[tid];
    float4 b  = x4[tid + 256];
    float4 wa = w4[tid];
    float4 wb = w4[tid + 256];
    float4 ga = g4[tid];          // issued early; consumed only in epilogue
    float4 gb = g4[tid + 256];

    // clear round-0 histogram (thread owns bins [8t, 8t+8))
    const uint4 zero4 = make_uint4(0u, 0u, 0u, 0u);
    uint4* h4 = (uint4*)hist;
    h4[2*tid]     = zero4;
    h4[2*tid + 1] = zero4;

    // ---- sum of squares -> rms ----
    float ss = a.x*a.x + a.y*a.y + a.z*a.z + a.w*a.w
             + b.x*b.x + b.y*b.y + b.z*b.z + b.w*b.w;
    #pragma unroll
    for (int off = 32; off > 0; off >>= 1)
        ss += __shfl_down(ss, off, 64);
    if (lane == 0) wsumf[wid] = ss;
    __syncthreads();                       // B0: wsumf visible + hist cleared
    const float total = wsumf[0] + wsumf[1] + wsumf[2] + wsumf[3];
    const float rms = rsqrtf(total * (1.0f / (float)DDIM) + 1e-6f);

    // ---- x_norm and magnitude bit patterns ----
    float nx[8];
    unsigned mb[8];
    nx[0] = a.x * rms * wa.x;  nx[1] = a.y * rms * wa.y;
    nx[2] = a.z * rms * wa.z;  nx[3] = a.w * rms * wa.w;
    nx[4] = b.x * rms * wb.x;  nx[5] = b.y * rms * wb.y;
    nx[6] = b.z * rms * wb.z;  nx[7] = b.w * rms * wb.w;
    #pragma unroll
    for (int i = 0; i < 8; ++i)
        mb[i] = __float_as_uint(fabsf(nx[i]));

    // ---- radix select: exact k-th largest magnitude ----
    unsigned kk = (unsigned)kp[0];
    unsigned prefix = 0;

    const int      shifts[3] = {20, 9, 0};
    const unsigned dmask[3]  = {0x7FFu, 0x7FFu, 0x1FFu};
    const unsigned himask[3] = {0u, 0xFFF00000u, 0xFFFFFE00u};

    #pragma unroll
    for (int r = 0; r < 3; ++r) {
        const int shift = shifts[r];
        // histogram (rounds 1-2: only elements matching decided prefix)
        #pragma unroll
        for (int i = 0; i < 8; ++i) {
            if ((mb[i] & himask[r]) == prefix)
                atomicAdd(&hist[(mb[i] >> shift) & dmask[r]], 1u);
        }
        __syncthreads();                   // A: counts ready

        // suffix-scan over 2048 bins: cge[bin] = #{ mags with digit >= bin }
        uint4 h0 = h4[2*tid];
        uint4 h1 = h4[2*tid + 1];
        unsigned c[8] = {h0.x, h0.y, h0.z, h0.w, h1.x, h1.y, h1.z, h1.w};
        unsigned sfx[8];
        sfx[7] = c[7];
        #pragma unroll
        for (int i = 6; i >= 0; --i) sfx[i] = sfx[i+1] + c[i];
        const unsigned T = sfx[0];
        unsigned suf = T;                  // sum of T over lanes >= lane
        #pragma unroll
        for (int off = 1; off < 64; off <<= 1) {
            unsigned t = __shfl_down(suf, off, 64);
            if (lane + off < 64) suf += t;
        }
        if (lane == 0) wtot[wid] = suf;    // whole-wave total
        __syncthreads();                   // B: wtot ready; hist reads done

        unsigned above = suf - T;          // bins owned by higher threads
        #pragma unroll
        for (int w = 0; w < 4; ++w)
            if (w > wid) above += wtot[w];
        #pragma unroll
        for (int i = 0; i < 8; ++i) {
            const unsigned cge = above + sfx[i];
            const unsigned cgt = cge - c[i];
            if (cgt < kk && kk <= cge) {   // unique crossing bin
                s_prefix = prefix | ((unsigned)(8*tid + i) << shift);
                s_kk = kk - cgt;
            }
        }
        if (r < 2) {                       // clear for next round
            h4[2*tid]     = zero4;
            h4[2*tid + 1] = zero4;
        }
        __syncthreads();                   // C: s_prefix visible + clear done
        prefix = s_prefix;
        kk = s_kk;
    }

    const unsigned thr = prefix;           // exact k-th largest |x_norm| bits

    // ---- epilogue: out = x + (|xn| >= thr) * xn * gamma ----
    float4 o1, o2;
    o1.x = a.x + (mb[0] >= thr ? nx[0] * ga.x : 0.0f);
    o1.y = a.y + (mb[1] >= thr ? nx[1] * ga.y : 0.0f);
    o1.z = a.z + (mb[2] >= thr ? nx[2] * ga.z : 0.0f);
    o1.w = a.w + (mb[3] >= thr ? nx[3] * ga.w : 0.0f);
    o2.x = b.x + (mb[4] >= thr ? nx[4] * gb.x : 0.0f);
    o2.y = b.y + (mb[5] >= thr ? nx[5] * gb.y : 0.0f);
    o2.z = b.z + (mb[6] >= thr ? nx[6] * gb.z : 0.0f);
    o2.w = b.w + (mb[7] >= thr ? nx[7] * gb.w : 0.0f);

    float4* out4 = (float4*)(out + row * (long)DDIM);
    out4[tid]       = o1;
    out4[tid + 256] = o2;
}

extern "C" void kernel_launch(void* const* d_in, const int* in_sizes, int n_in,
                              void* d_out, int out_size, void* d_ws, size_t ws_size,
                              hipStream_t stream) {
    const float* x      = (const float*)d_in[0];
    const float* weight = (const float*)d_in[1];
    const float* gamma  = (const float*)d_in[2];
    const int*   kp     = (const int*)d_in[3];
    const int D = in_sizes[1];          // 2048
    const int N = in_sizes[0] / D;      // 32768
    (void)n_in; (void)out_size; (void)d_ws; (void)ws_size;

    sparse_topk_rmsnorm_kernel<<<dim3(N), dim3(THREADS), 0, stream>>>(
        x, weight, gamma, kp, (float*)d_out);
}